// Round 10
// baseline (216.425 us; speedup 1.0000x reference)
//
#include <hip/hip_runtime.h>

// RNMF encoder, MI355X. Identities:
//   b_k = b_0 + H z_k (ISTA telescopes) => z <- relu(b0 + H z - t), 16x
//   V = D z_q + z_m ;          zm' = relu(bmt + (1-0.1e) zm - e*V)
//   G = D^T D:  D^T V = G z_q + D^T z_m  (both GEMMs depend only on OLD z)
//   zq' = relu(bqt + (1-0.1e) zq - e*(G zq + DT zm))
// History: R3 120us; R4/R10 spills prove unified-RF cap (~2x arch VGPR count;
//   (256,w) caps arch at ~256/w). R5/R6 flat at pair-geometry. R8: total-main
//   ~104-107us constant = harness+prep floor. R9 4-way row-split 109.5us
//   (occupancy 30% = RF ceiling). R11 VALU trim: flat, VALUBusy ~46 unchanged.
// R12: ONE barrier/iter at R9 geometry. G-identity makes GEMM1 and GEMM2
//   independent within an iteration -> publish {zq', zm'} to double-buffered
//   exchange, single barrier. 18 MFMA/wave-iter (+2 for G), chains depth<=6,
//   LDS bytes unchanged (zmb replaces vb, identical frag addressing).
//   Prep additionally stores Gbf = (-eta)*G bf16 (R6-validated numerics).

typedef __bf16 bf16x8 __attribute__((ext_vector_type(8)));
typedef float f32x4 __attribute__((ext_vector_type(4)));

#define MFMA16(a, b, c) __builtin_amdgcn_mfma_f32_16x16x32_bf16((a), (b), (c), 0, 0, 0)

#define NTOT 65536
#define NCOL 16

__device__ __forceinline__ unsigned pk2(float a, float b) {
#if __has_builtin(__builtin_amdgcn_cvt_pk_bf16_f32)
  return __builtin_bit_cast(unsigned, __builtin_amdgcn_cvt_pk_bf16_f32(a, b));
#else
  unsigned short ua = __builtin_bit_cast(unsigned short, (__bf16)a);
  unsigned short ub = __builtin_bit_cast(unsigned short, (__bf16)b);
  return (unsigned)ua | ((unsigned)ub << 16);
#endif
}
__device__ __forceinline__ f32x4 f4(float s) { f32x4 v = {s, s, s, s}; return v; }
__device__ __forceinline__ f32x4 pfma4(f32x4 a, f32x4 b, f32x4 c) {
  return __builtin_elementwise_fma(a, b, c);
}
__device__ __forceinline__ f32x4 pmax04(f32x4 a) {
  return __builtin_elementwise_max(a, f4(0.f));
}

// ---------------- Kernel 0: prep (3 blocks, 256 threads) ----------------
// ws: [0..255] header (wsf[0]=eta), +256: Dbf [256][64] bf16 (unscaled),
//     +256+32768: DTbf [64][256] bf16 = (-eta)*D^T,
//     +256+65536: Gbf  [64][64]  bf16 = (-eta)*G   (G = D^T D).
// block 0: eta pipeline + prescaled DTbf/Gbf; blocks 1,2: Dbf staging halves.
#define GOF(row) ((row) * 68 + (((row) >> 3) << 2))   // skewed fp32 row offset (16B-aligned)
__global__ void rnmf_prep(const float* __restrict__ D, void* __restrict__ ws) {
  float* wsf = (float*)ws;
  __bf16* Dbf = (__bf16*)((char*)ws + 256);
  __bf16* DTbf = (__bf16*)((char*)ws + 256 + 32768);
  __bf16* Gbf = (__bf16*)((char*)ws + 256 + 65536);

  const int tid = threadIdx.x;

  if (blockIdx.x != 0) {
    const int bs = blockIdx.x - 1;   // 0 or 1: half of Dbf each
#pragma unroll
    for (int e = 0; e < 8; ++e) {
      int i4 = bs * 2048 + e * 256 + tid;
      float4 dv = *(const float4*)(D + i4 * 4);
      uint2 u; u.x = pk2(dv.x, dv.y); u.y = pk2(dv.z, dv.w);
      *(uint2*)(Dbf + i4 * 4) = u;
    }
    return;
  }

  // ---- block 0: eta pipeline + prescaled DTbf/Gbf ----
  __shared__ __bf16 DTl[64 * 264];   // D^T, [a][k] stride 264
  __shared__ __bf16 gA[64 * 72];
  __shared__ __bf16 gB[64 * 72];
  __shared__ __bf16 gG[64 * 72];     // bf16 G preserved (gA gets overwritten)
  __shared__ float gf[64 * 68 + 32]; // G^8 fp32, skewed rows
  __shared__ __align__(16) float xv[64];
  __shared__ float etas;

  const int w = tid >> 6, lane = tid & 63, c = lane & 15, q4 = lane >> 4;

#pragma unroll
  for (int e = 0; e < 64; ++e) {
    int flat = e * 256 + tid;
    int k = flat >> 6, a = flat & 63;
    DTl[a * 264 + k] = (__bf16)D[k * 64 + a];
  }
  __syncthreads();
  // G = D^T D  (keep a copy in gG)
#pragma unroll
  for (int ct = 0; ct < 4; ++ct) {
    f32x4 acc = {0.f, 0.f, 0.f, 0.f};
#pragma unroll
    for (int kb = 0; kb < 8; ++kb) {
      bf16x8 a = *(const bf16x8*)&DTl[(16 * w + c) * 264 + 32 * kb + 8 * q4];
      bf16x8 b = *(const bf16x8*)&DTl[(16 * ct + c) * 264 + 32 * kb + 8 * q4];
      acc = MFMA16(a, b, acc);
    }
#pragma unroll
    for (int r = 0; r < 4; ++r) {
      __bf16 gv = (__bf16)acc[r];
      gA[(16 * w + 4 * q4 + r) * 72 + 16 * ct + c] = gv;
      gG[(16 * w + 4 * q4 + r) * 72 + 16 * ct + c] = gv;
    }
  }
  __syncthreads();
  // G2
#pragma unroll
  for (int ct = 0; ct < 4; ++ct) {
    f32x4 acc = {0.f, 0.f, 0.f, 0.f};
#pragma unroll
    for (int kb = 0; kb < 2; ++kb) {
      bf16x8 a = *(const bf16x8*)&gA[(16 * w + c) * 72 + 32 * kb + 8 * q4];
      bf16x8 b = *(const bf16x8*)&gA[(16 * ct + c) * 72 + 32 * kb + 8 * q4];
      acc = MFMA16(a, b, acc);
    }
#pragma unroll
    for (int r = 0; r < 4; ++r)
      gB[(16 * w + 4 * q4 + r) * 72 + 16 * ct + c] = (__bf16)acc[r];
  }
  __syncthreads();
  // G4
#pragma unroll
  for (int ct = 0; ct < 4; ++ct) {
    f32x4 acc = {0.f, 0.f, 0.f, 0.f};
#pragma unroll
    for (int kb = 0; kb < 2; ++kb) {
      bf16x8 a = *(const bf16x8*)&gB[(16 * w + c) * 72 + 32 * kb + 8 * q4];
      bf16x8 b = *(const bf16x8*)&gB[(16 * ct + c) * 72 + 32 * kb + 8 * q4];
      acc = MFMA16(a, b, acc);
    }
#pragma unroll
    for (int r = 0; r < 4; ++r)
      gA[(16 * w + 4 * q4 + r) * 72 + 16 * ct + c] = (__bf16)acc[r];
  }
  __syncthreads();
  // G8 -> fp32
#pragma unroll
  for (int ct = 0; ct < 4; ++ct) {
    f32x4 acc = {0.f, 0.f, 0.f, 0.f};
#pragma unroll
    for (int kb = 0; kb < 2; ++kb) {
      bf16x8 a = *(const bf16x8*)&gA[(16 * w + c) * 72 + 32 * kb + 8 * q4];
      bf16x8 b = *(const bf16x8*)&gA[(16 * ct + c) * 72 + 32 * kb + 8 * q4];
      acc = MFMA16(a, b, acc);
    }
#pragma unroll
    for (int r = 0; r < 4; ++r)
      gf[GOF(16 * w + 4 * q4 + r) + 16 * ct + c] = acc[r];
  }
  __syncthreads();

  if (w == 0) {
    float td = gf[GOF(lane) + lane];
#pragma unroll
    for (int off = 32; off; off >>= 1) td += __shfl_xor(td, off, 64);
    const float tr = td;
    const float itr = 1.f / tr;
    xv[lane] = 1.f;
    float nm = 1.f;
    const int rowoff = GOF(lane);
    for (int itp = 0; itp < 28; ++itp) {
      float a0 = 0.f, a1 = 0.f, a2 = 0.f, a3 = 0.f;
#pragma unroll
      for (int k = 0; k < 64; k += 16) {
        float4 ga = *(const float4*)&gf[rowoff + k];
        float4 xa = *(const float4*)&xv[k];
        float4 gb = *(const float4*)&gf[rowoff + k + 4];
        float4 xb = *(const float4*)&xv[k + 4];
        float4 gc = *(const float4*)&gf[rowoff + k + 8];
        float4 xc = *(const float4*)&xv[k + 8];
        float4 gd = *(const float4*)&gf[rowoff + k + 12];
        float4 xd = *(const float4*)&xv[k + 12];
        a0 = fmaf(ga.x, xa.x, a0); a0 = fmaf(ga.y, xa.y, a0);
        a0 = fmaf(ga.z, xa.z, a0); a0 = fmaf(ga.w, xa.w, a0);
        a1 = fmaf(gb.x, xb.x, a1); a1 = fmaf(gb.y, xb.y, a1);
        a1 = fmaf(gb.z, xb.z, a1); a1 = fmaf(gb.w, xb.w, a1);
        a2 = fmaf(gc.x, xc.x, a2); a2 = fmaf(gc.y, xc.y, a2);
        a2 = fmaf(gc.z, xc.z, a2); a2 = fmaf(gc.w, xc.w, a2);
        a3 = fmaf(gd.x, xd.x, a3); a3 = fmaf(gd.y, xd.y, a3);
        a3 = fmaf(gd.z, xd.z, a3); a3 = fmaf(gd.w, xd.w, a3);
      }
      float acc = (a0 + a1) + (a2 + a3);
      float y = acc * itr;
      float n2 = y * y;
#pragma unroll
      for (int off = 32; off; off >>= 1) n2 += __shfl_xor(n2, off, 64);
      nm = sqrtf(n2);
      xv[lane] = y / nm;
    }
    if (lane == 0) {
      float e = 1.f / powf(nm * tr, 0.125f);  // eta = 1/alpha
      wsf[0] = e;
      etas = e;
    }
  }
  __syncthreads();   // etas visible; DTl/gG intact

  const float msc = -etas;
  // DTbf = (-eta) * D^T
#pragma unroll
  for (int e = 0; e < 8; ++e) {
    int fi = e * 256 + tid;
    int a2 = fi >> 5;
    int k2 = (fi * 8) & 255;
    const __bf16* src = &DTl[a2 * 264 + k2];
    uint4 o;
    o.x = pk2(msc * (float)src[0], msc * (float)src[1]);
    o.y = pk2(msc * (float)src[2], msc * (float)src[3]);
    o.z = pk2(msc * (float)src[4], msc * (float)src[5]);
    o.w = pk2(msc * (float)src[6], msc * (float)src[7]);
    *(uint4*)(DTbf + fi * 8) = o;
  }
  // Gbf = (-eta) * G  (4096 bf16)
#pragma unroll
  for (int e = 0; e < 2; ++e) {
    int fi = e * 256 + tid;
    int row = fi >> 3;
    int c8 = (fi & 7) * 8;
    const __bf16* src = &gG[row * 72 + c8];
    uint4 o;
    o.x = pk2(msc * (float)src[0], msc * (float)src[1]);
    o.y = pk2(msc * (float)src[2], msc * (float)src[3]);
    o.z = pk2(msc * (float)src[4], msc * (float)src[5]);
    o.w = pk2(msc * (float)src[6], msc * (float)src[7]);
    *(uint4*)(Gbf + row * 64 + c8) = o;
  }
}

// ---------------- Kernel 1: main (4096 blocks x 256 thr, 16 cols/block) -----
// 4-way row-split waves (R9 geometry). Wave w:
//   GEMM1: zm rows [64w, 64w+64); C-in = zm -> MFMA emits V
//   GEMM2: zq rows [16w, 16w+16); s = bqt - eta*(G zq + DT zm) via C-in chains
// ONE barrier per iteration: both GEMMs read old {zqb, zmb} from buf[cur],
// publish {zq', zm'} to buf[nxt]. Double-buffered, 10240 B per buffer:
//   zqb [kb<2][1024] at +0, zmb [kb<8][1024] at +2048.
// phase A overlay: xs = fp32 X tile [col][row], stride 260 (16640 B).
__global__ __launch_bounds__(256, 3) void rnmf_main(const float* __restrict__ X,
                                                    float* __restrict__ Z,
                                                    const void* __restrict__ ws) {
  const float* wsf = (const float*)ws;
  const __bf16* Dbf = (const __bf16*)((const char*)ws + 256);
  const __bf16* DTbf = (const __bf16*)((const char*)ws + 256 + 32768);
  const __bf16* Gbf = (const __bf16*)((const char*)ws + 256 + 65536);

  __shared__ __align__(16) char arena[20480];
  float* xs = (float*)arena;
  char* smem = arena;

  const int tid = threadIdx.x;
  const int w = tid >> 6;          // 0..3: row-quarter
  const int lane = tid & 63;
  const int c = lane & 15;
  const int q4 = lane >> 4;
  const int q4h = q4 >> 1, q4l = q4 & 1;
  const int j0 = blockIdx.x * NCOL;

  // stage X tile: coalesced float4 global loads, scalar LDS scatter (one-time)
#pragma unroll
  for (int e = 0; e < 4; ++e) {
    int idx = e * 256 + tid;                  // float4 id, 1024 total
    int row = idx >> 2, c4 = (idx & 3) * 4;
    float4 g = *(const float4*)(X + row * NTOT + j0 + c4);
    xs[(c4 + 0) * 260 + row] = g.x;
    xs[(c4 + 1) * 260 + row] = g.y;
    xs[(c4 + 2) * 260 + row] = g.z;
    xs[(c4 + 3) * 260 + row] = g.w;
  }

  const float eta = wsf[0];
  const f32x4 etav = f4(eta);
  const f32x4 metav = f4(-eta);
  const f32x4 cqv = f4(1.f - 0.1f * eta);   // cm + eta == cq: one constant
  const float tm = 0.1f * eta;

  // D/G fragments (iteration-invariant, register-resident)
  bf16x8 d1[4][2];   // GEMM1 A: D rows [64w..64w+64), K=64 (unscaled)
#pragma unroll
  for (int rt = 0; rt < 4; ++rt)
#pragma unroll
    for (int kb = 0; kb < 2; ++kb)
      d1[rt][kb] = *(const bf16x8*)(Dbf + (64 * w + 16 * rt + c) * 64 + 32 * kb + 8 * q4);
  bf16x8 d2[8];      // GEMM2 A: (-eta)*D^T rows [16w..16w+16), K=256
#pragma unroll
  for (int kb = 0; kb < 8; ++kb)
    d2[kb] = *(const bf16x8*)(DTbf + (16 * w + c) * 256 + 32 * kb + 8 * q4);
  bf16x8 gq[2];      // (-eta)*G rows [16w..16w+16), K=64
#pragma unroll
  for (int kb = 0; kb < 2; ++kb)
    gq[kb] = *(const bf16x8*)(Gbf + (16 * w + c) * 64 + 32 * kb + 8 * q4);

  __syncthreads();   // xs staged

  // pack NEGATED x stripe (K=256): d2'*(-x) = eta*D^T x = bqt directly
  bf16x8 xbn[8];
#pragma unroll
  for (int kb = 0; kb < 8; ++kb) {
    const float* p = &xs[c * 260 + 32 * kb + 8 * q4];
    float4 lo = *(const float4*)p;
    float4 hi = *(const float4*)(p + 4);
    uint4 packed = {pk2(-lo.x, -lo.y), pk2(-lo.z, -lo.w), pk2(-hi.x, -hi.y), pk2(-hi.z, -hi.w)};
    xbn[kb] = __builtin_bit_cast(bf16x8, packed);
  }

  // bqt = eta * D^T x (this wave's 16 zq rows); 2 independent 4-chains
  f32x4 bqt4;
  {
    f32x4 aA = {0.f, 0.f, 0.f, 0.f}, aB = {0.f, 0.f, 0.f, 0.f};
#pragma unroll
    for (int kb = 0; kb < 4; ++kb) aA = MFMA16(d2[kb], xbn[kb], aA);
#pragma unroll
    for (int kb = 4; kb < 8; ++kb) aB = MFMA16(d2[kb], xbn[kb], aB);
    bqt4 = aA + aB;   // t_q = 0
  }

  // bmt = eta*x - tm (exact fp32); rows 4q4+0..3 match the MFMA C/D layout
  f32x4 bmt4[4];
#pragma unroll
  for (int rt = 0; rt < 4; ++rt) {
    const float* p = &xs[c * 260 + 64 * w + 16 * rt + 4 * q4];
    float4 v = *(const float4*)p;
    f32x4 x4 = {v.x, v.y, v.z, v.w};
    bmt4[rt] = pfma4(etav, x4, f4(-tm));
  }

  __syncthreads();   // xs dead -> arena reusable as buffers

  // z1 = relu(b0 - t)
  f32x4 zq4 = pmax04(bqt4);
  f32x4 zm4[4];
#pragma unroll
  for (int rt = 0; rt < 4; ++rt) zm4[rt] = pmax04(bmt4[rt]);

  // per-lane LDS byte offsets (buffer-relative; reads are base + lane*16)
  const int rb = lane * 16;
  const int wzq = w * 512 + q4h * 256 + c * 16 + 8 * q4l;
  const int wzm = 2048 + w * 2048 + q4h * 256 + c * 16 + 8 * q4l;   // + rt*512

  // publish z1 {zq, zm} to buf0
  {
    uint2 u; u.x = pk2(zq4[0], zq4[1]); u.y = pk2(zq4[2], zq4[3]);
    *(uint2*)(smem + wzq) = u;
  }
#pragma unroll
  for (int rt = 0; rt < 4; ++rt) {
    uint2 u; u.x = pk2(zm4[rt][0], zm4[rt][1]); u.y = pk2(zm4[rt][2], zm4[rt][3]);
    *(uint2*)(smem + wzm + rt * 512) = u;
  }

  auto ITER = [&](const int cb, const int nb) {
    __syncthreads();   // buf[cb] ready; buf[nb] free (fully consumed last iter)
    bf16x8 zqf0 = *(const bf16x8*)(smem + cb + rb);
    bf16x8 zqf1 = *(const bf16x8*)(smem + cb + 1024 + rb);
    // GEMM2 head: aA = bqt - eta*G zq (C-in seeded, depth 2 so far)
    f32x4 aA = MFMA16(gq[0], zqf0, bqt4);
    aA = MFMA16(gq[1], zqf1, aA);
    // GEMM1: V = D zq + zm (C-in); zm' = relu(bmt + cq*zm - eta*V); publish zm'
#pragma unroll
    for (int rt = 0; rt < 4; ++rt) {
      f32x4 V = MFMA16(d1[rt][0], zqf0, zm4[rt]);
      V = MFMA16(d1[rt][1], zqf1, V);
      zm4[rt] = pmax04(pfma4(metav, V, pfma4(cqv, zm4[rt], bmt4[rt])));
      uint2 uu; uu.x = pk2(zm4[rt][0], zm4[rt][1]); uu.y = pk2(zm4[rt][2], zm4[rt][3]);
      *(uint2*)(smem + nb + wzm + rt * 512) = uu;
    }
    // GEMM2 tail: += -eta*DT zm(old) over 2 chains (depth 6 / 4)
    f32x4 aB = {0.f, 0.f, 0.f, 0.f};
#pragma unroll
    for (int kb = 0; kb < 4; ++kb) {
      bf16x8 zmf = *(const bf16x8*)(smem + cb + 2048 + kb * 1024 + rb);
      aA = MFMA16(d2[kb], zmf, aA);
    }
#pragma unroll
    for (int kb = 4; kb < 8; ++kb) {
      bf16x8 zmf = *(const bf16x8*)(smem + cb + 2048 + kb * 1024 + rb);
      aB = MFMA16(d2[kb], zmf, aB);
    }
    f32x4 s = aA + aB;
    zq4 = pmax04(pfma4(cqv, zq4, s));   // relu(cq*zq + bqt - eta*(G zq + DT zm))
    uint2 u; u.x = pk2(zq4[0], zq4[1]); u.y = pk2(zq4[2], zq4[3]);
    *(uint2*)(smem + nb + wzq) = u;
  };

#pragma unroll 1
  for (int it2 = 0; it2 < 7; ++it2) {
    ITER(0, 10240);
    ITER(10240, 0);
  }
  ITER(0, 10240);   // 15th iteration -> z16 in registers

  // store Z: rows 0..63 = q-part, rows 64..319 = m-part
#pragma unroll
  for (int j = 0; j < 4; ++j)
    Z[(16 * w + 4 * q4 + j) * NTOT + j0 + c] = zq4[j];
#pragma unroll
  for (int rt = 0; rt < 4; ++rt)
#pragma unroll
    for (int j = 0; j < 4; ++j)
      Z[(64 + 64 * w + 16 * rt + 4 * q4 + j) * NTOT + j0 + c] = zm4[rt][j];
}

extern "C" void kernel_launch(void* const* d_in, const int* in_sizes, int n_in,
                              void* d_out, int out_size, void* d_ws, size_t ws_size,
                              hipStream_t stream) {
  const float* X = (const float*)d_in[0];
  const float* D = (const float*)d_in[1];
  float* Z = (float*)d_out;
  rnmf_prep<<<dim3(3), dim3(256), 0, stream>>>(D, d_ws);
  rnmf_main<<<dim3(NTOT / NCOL), dim3(256), 0, stream>>>(X, Z, d_ws);
}